// Round 4
// baseline (236.245 us; speedup 1.0000x reference)
//
#include <hip/hip_runtime.h>
#include <hip/hip_bf16.h>

#define IMAGE_SIZE 416
#define DECODED 64
#define NPIX (IMAGE_SIZE * IMAGE_SIZE)   // 173056
#define M_OBJ 128                        // B*N = 4*32
#define D_IN 64
#define H1 512
#define OUT2 12288                       // 3*64*64

// ---------------- Kernel 1: per-object params + present-compaction ----------
// obj layout per object (8 floats): tx, ty, inv_sx, inv_sy, weight, slot, 0,0
__global__ __launch_bounds__(128) void wts_kernel(const float* __restrict__ z_where,
                                                  const int* __restrict__ z_present,
                                                  const float* __restrict__ z_depth,
                                                  float* __restrict__ obj,
                                                  int* __restrict__ comp,
                                                  int* __restrict__ cnt) {
    const int t = threadIdx.x;       // 0..127 -> (b = t>>5, n = t&31)
    const int b = t >> 5;
    __shared__ float sd[128];
    __shared__ float se[128];
    __shared__ int spres[128];
    __shared__ int sslot[128];

    const int pres = z_present[t];
    spres[t] = pres;
    const float d = pres ? z_depth[t] : -1000.0f;
    sd[t] = d;
    __syncthreads();

    float m = -1e30f;
#pragma unroll
    for (int k = 0; k < 32; ++k) m = fmaxf(m, sd[(b << 5) + k]);
    const float e = expf(d - m);
    se[t] = e;
    __syncthreads();

    float s = 0.0f;
#pragma unroll
    for (int k = 0; k < 32; ++k) s += se[(b << 5) + k];
    const float wgt = pres ? (e / s) : 0.0f;

    if (t == 0) {
        for (int i = 0; i < 128; ++i) comp[i] = i;  // init: any stray read is safe
        int c = 0;
        for (int i = 0; i < 128; ++i) {
            sslot[i] = spres[i] ? c : -1;
            if (spres[i]) comp[c++] = i;
        }
        *cnt = c;
    }
    __syncthreads();

    const float xc = z_where[t * 4 + 0];
    const float yc = z_where[t * 4 + 1];
    const float ww = z_where[t * 4 + 2];
    const float hh = z_where[t * 4 + 3];
    float* o = obj + t * 8;
    o[0] = 2.0f * xc - 1.0f;
    o[1] = 2.0f * yc - 1.0f;
    o[2] = 1.0f / fmaxf(ww, 0.001f);
    o[3] = 1.0f / fmaxf(hh, 0.001f);
    o[4] = wgt;
    o[5] = (float)sslot[t];
    o[6] = 0.0f; o[7] = 0.0f;
}

__device__ __forceinline__ int safe_count(const int* cnt) {
    int c = *cnt;
    return min(max(c, 1), 128);   // never trust workspace state for addressing
}

// ---------------- Kernel 2: hid[ci] = relu(z_what[comp[ci]] @ w1 + b1) -------
__global__ __launch_bounds__(512) void mlp1_kernel(const float* __restrict__ z_what,
                                                   const float* __restrict__ w1,
                                                   const float* __restrict__ b1,
                                                   float* __restrict__ hid,
                                                   const int* __restrict__ comp,
                                                   const int* __restrict__ cnt) {
    const int ci = blockIdx.x;
    if (ci >= safe_count(cnt)) return;
    const int orig = min(max(comp[ci], 0), 127);
    const int h = threadIdx.x;
    const float* zr = z_what + orig * D_IN;   // uniform per block -> scalar loads
    float acc = b1[h];
#pragma unroll
    for (int d = 0; d < D_IN; ++d)
        acc = fmaf(zr[d], w1[d * H1 + h], acc);
    hid[ci * H1 + h] = fmaxf(acc, 0.0f);
}

// ---------------- Kernel 3: dec[ci] = sigmoid(hid[ci] @ w2 + b2) -------------
// Block = 1024 threads = 4 k-groups x 256 cols. Each group: 16 rows x 256 cols
// over a 128-wide K chunk (8-deep double-buffered w2 prefetch). Groups 1..3
// write partials to LDS; group 0 reduces + sigmoid + stores.
// Grid: (48 col-tiles, 8 row-tiles). ~4 waves/SIMD active on occupied CUs.
__global__ __launch_bounds__(1024) void mlp2_kernel(const float* __restrict__ hid,
                                                    const float* __restrict__ w2,
                                                    const float* __restrict__ b2,
                                                    float* __restrict__ dec,
                                                    const int* __restrict__ cnt) {
    const int count = safe_count(cnt);
    const int ci0 = blockIdx.y * 16;
    if (ci0 >= count) return;

    const int kg = threadIdx.x >> 8;          // k-group 0..3
    const int lj = threadIdx.x & 255;         // local col 0..255
    const int j = blockIdx.x * 256 + lj;      // output column 0..12287
    const int kbase = kg * 128;

    __shared__ float sred[3][16][256];        // 48 KB partial-sum staging

    float acc[16];
#pragma unroll
    for (int r = 0; r < 16; ++r) acc[r] = 0.0f;

    const float* hrow = hid + ci0 * H1 + kbase;  // uniform -> scalar-load path
    const float* wp = w2 + (size_t)kbase * OUT2 + j;

    float wa[8], wb[8];
#pragma unroll
    for (int u = 0; u < 8; ++u) wa[u] = wp[(size_t)u * OUT2];

    for (int k0 = 0; k0 < 128; k0 += 16) {
#pragma unroll
        for (int u = 0; u < 8; ++u) wb[u] = wp[(size_t)(k0 + 8 + u) * OUT2];
#pragma unroll
        for (int u = 0; u < 8; ++u)
#pragma unroll
            for (int r = 0; r < 16; ++r)
                acc[r] = fmaf(hrow[r * H1 + k0 + u], wa[u], acc[r]);
        if (k0 + 16 < 128) {
#pragma unroll
            for (int u = 0; u < 8; ++u) wa[u] = wp[(size_t)(k0 + 16 + u) * OUT2];
        }
#pragma unroll
        for (int u = 0; u < 8; ++u)
#pragma unroll
            for (int r = 0; r < 16; ++r)
                acc[r] = fmaf(hrow[r * H1 + k0 + 8 + u], wb[u], acc[r]);
    }

    if (kg > 0) {
#pragma unroll
        for (int r = 0; r < 16; ++r) sred[kg - 1][r][lj] = acc[r];
    }
    __syncthreads();

    if (kg == 0) {
        const float bb = b2[j];
        const int rmax = min(16, count - ci0);
        for (int r = 0; r < rmax; ++r) {
            float x = acc[r] + sred[0][r][lj] + sred[1][r][lj] + sred[2][r][lj] + bb;
            float v = 1.0f / (1.0f + __expf(-x));
            dec[(size_t)(ci0 + r) * OUT2 + j] = v;
        }
    }
}

// ---------------- Kernel 4: composite --------------------------------------
__global__ __launch_bounds__(256) void composite_kernel(const float* __restrict__ dec,
                                                        const float* __restrict__ obj,
                                                        float* __restrict__ out) {
    const int pix = blockIdx.x * 256 + threadIdx.x;  // 0..173055
    const int b = blockIdx.y;
    const int h = pix / IMAGE_SIZE;
    const int w = pix - h * IMAGE_SIZE;

    __shared__ float sobj[32 * 8];
    for (int k = threadIdx.x; k < 32 * 8; k += 256) sobj[k] = obj[b * 32 * 8 + k];
    __syncthreads();

    const float u = fmaf((float)w, 2.0f / 415.0f, -1.0f);
    const float v = fmaf((float)h, 2.0f / 415.0f, -1.0f);

    float a0 = 0.0f, a1 = 0.0f, a2 = 0.0f;

    for (int n = 0; n < 32; ++n) {
        const float wgt = sobj[n * 8 + 4];
        if (wgt == 0.0f) continue;
        const float gx = (u - sobj[n * 8 + 0]) * sobj[n * 8 + 2];
        const float gy = (v - sobj[n * 8 + 1]) * sobj[n * 8 + 3];
        const float px = (gx + 1.0f) * (0.5f * (DECODED - 1));  // *31.5
        const float py = (gy + 1.0f) * (0.5f * (DECODED - 1));
        if (px <= -1.0f || px >= (float)DECODED || py <= -1.0f || py >= (float)DECODED)
            continue;  // all four corners invalid -> contributes 0

        const float x0f = floorf(px), y0f = floorf(py);
        const int x0 = (int)x0f, y0 = (int)y0f;
        const float wx1 = px - x0f, wx0 = 1.0f - wx1;
        const float wy1 = py - y0f, wy0 = 1.0f - wy1;

        const bool vx0 = (x0 >= 0) & (x0 <= DECODED - 1);
        const bool vx1 = (x0 + 1 >= 0) & (x0 + 1 <= DECODED - 1);
        const bool vy0 = (y0 >= 0) & (y0 <= DECODED - 1);
        const bool vy1 = (y0 + 1 >= 0) & (y0 + 1 <= DECODED - 1);

        const int xc0 = min(max(x0, 0), DECODED - 1);
        const int xc1 = min(max(x0 + 1, 0), DECODED - 1);
        const int yc0 = min(max(y0, 0), DECODED - 1);
        const int yc1 = min(max(y0 + 1, 0), DECODED - 1);

        const float w00 = wx0 * wy0 * (float)(vx0 && vy0);
        const float w10 = wx1 * wy0 * (float)(vx1 && vy0);
        const float w01 = wx0 * wy1 * (float)(vx0 && vy1);
        const float w11 = wx1 * wy1 * (float)(vx1 && vy1);

        const int slot = min(max((int)sobj[n * 8 + 5], 0), 127);  // clamp: no wild addr
        const float* base = dec + (size_t)slot * OUT2;
        const int i00 = yc0 * DECODED + xc0;
        const int i10 = yc0 * DECODED + xc1;
        const int i01 = yc1 * DECODED + xc0;
        const int i11 = yc1 * DECODED + xc1;

        {
            const float* p = base;  // channel 0
            float g = w00 * p[i00] + w10 * p[i10] + w01 * p[i01] + w11 * p[i11];
            a0 = fmaf(wgt, g, a0);
        }
        {
            const float* p = base + 4096;  // channel 1
            float g = w00 * p[i00] + w10 * p[i10] + w01 * p[i01] + w11 * p[i11];
            a1 = fmaf(wgt, g, a1);
        }
        {
            const float* p = base + 8192;  // channel 2
            float g = w00 * p[i00] + w10 * p[i10] + w01 * p[i01] + w11 * p[i11];
            a2 = fmaf(wgt, g, a2);
        }
    }

    out[((size_t)(b * 3 + 0) * IMAGE_SIZE + h) * IMAGE_SIZE + w] = a0;
    out[((size_t)(b * 3 + 1) * IMAGE_SIZE + h) * IMAGE_SIZE + w] = a1;
    out[((size_t)(b * 3 + 2) * IMAGE_SIZE + h) * IMAGE_SIZE + w] = a2;
}

extern "C" void kernel_launch(void* const* d_in, const int* in_sizes, int n_in,
                              void* d_out, int out_size, void* d_ws, size_t ws_size,
                              hipStream_t stream) {
    const float* z_where   = (const float*)d_in[0];   // [4,32,4]
    const int*   z_present = (const int*)d_in[1];     // [4,32,1]
    const float* z_what    = (const float*)d_in[2];   // [4,32,64]
    const float* z_depth   = (const float*)d_in[3];   // [4,32,1]
    const float* w1 = (const float*)d_in[4];          // [64,512]
    const float* b1 = (const float*)d_in[5];          // [512]
    const float* w2 = (const float*)d_in[6];          // [512,12288]
    const float* b2 = (const float*)d_in[7];          // [12288]
    float* out = (float*)d_out;                       // [4,3,416,416] f32

    char* ws = (char*)d_ws;
    float* dec = (float*)ws;                              // 6,291,456 B (by compact slot)
    float* hid = (float*)(ws + 6291456);                  //   262,144 B (by compact slot)
    float* obj = (float*)(ws + 6291456 + 262144);         //     4,096 B
    int*  comp = (int*)(ws + 6291456 + 262144 + 4096);    //       512 B
    int*  cnt  = (int*)(ws + 6291456 + 262144 + 4096 + 512);

    wts_kernel<<<1, 128, 0, stream>>>(z_where, z_present, z_depth, obj, comp, cnt);
    mlp1_kernel<<<M_OBJ, 512, 0, stream>>>(z_what, w1, b1, hid, comp, cnt);
    mlp2_kernel<<<dim3(48, 8), 1024, 0, stream>>>(hid, w2, b2, dec, cnt);
    composite_kernel<<<dim3(NPIX / 256, 4), 256, 0, stream>>>(dec, obj, out);
}

// Round 5
// 224.959 us; speedup vs baseline: 1.0502x; 1.0502x over previous
//
#include <hip/hip_runtime.h>
#include <hip/hip_bf16.h>

#define IMAGE_SIZE 416
#define DECODED 64
#define NPIX (IMAGE_SIZE * IMAGE_SIZE)   // 173056
#define M_OBJ 128                        // B*N = 4*32
#define D_IN 64
#define H1 512
#define OUT2 12288                       // 3*64*64

// ---------------- Kernel 1: per-object params + present-compaction ----------
// obj layout per object (8 floats): tx, ty, inv_sx, inv_sy, weight, slot, 0,0
__global__ __launch_bounds__(128) void wts_kernel(const float* __restrict__ z_where,
                                                  const int* __restrict__ z_present,
                                                  const float* __restrict__ z_depth,
                                                  float* __restrict__ obj,
                                                  int* __restrict__ comp,
                                                  int* __restrict__ cnt) {
    const int t = threadIdx.x;       // 0..127 -> (b = t>>5, n = t&31)
    const int b = t >> 5;
    __shared__ float sd[128];
    __shared__ float se[128];
    __shared__ int spres[128];
    __shared__ int sslot[128];

    const int pres = z_present[t];
    spres[t] = pres;
    const float d = pres ? z_depth[t] : -1000.0f;
    sd[t] = d;
    __syncthreads();

    float m = -1e30f;
#pragma unroll
    for (int k = 0; k < 32; ++k) m = fmaxf(m, sd[(b << 5) + k]);
    const float e = expf(d - m);
    se[t] = e;
    __syncthreads();

    float s = 0.0f;
#pragma unroll
    for (int k = 0; k < 32; ++k) s += se[(b << 5) + k];
    const float wgt = pres ? (e / s) : 0.0f;

    if (t == 0) {
        for (int i = 0; i < 128; ++i) comp[i] = i;  // init: any stray read is safe
        int c = 0;
        for (int i = 0; i < 128; ++i) {
            sslot[i] = spres[i] ? c : -1;
            if (spres[i]) comp[c++] = i;
        }
        *cnt = c;
    }
    __syncthreads();

    const float xc = z_where[t * 4 + 0];
    const float yc = z_where[t * 4 + 1];
    const float ww = z_where[t * 4 + 2];
    const float hh = z_where[t * 4 + 3];
    float* o = obj + t * 8;
    o[0] = 2.0f * xc - 1.0f;
    o[1] = 2.0f * yc - 1.0f;
    o[2] = 1.0f / fmaxf(ww, 0.001f);
    o[3] = 1.0f / fmaxf(hh, 0.001f);
    o[4] = wgt;
    o[5] = (float)sslot[t];
    o[6] = 0.0f; o[7] = 0.0f;
}

__device__ __forceinline__ int safe_count(const int* cnt) {
    int c = *cnt;
    return min(max(c, 1), 128);   // never trust workspace state for addressing
}

// ---------------- Kernel 2: hid[ci] = relu(z_what[comp[ci]] @ w1 + b1) -------
__global__ __launch_bounds__(512) void mlp1_kernel(const float* __restrict__ z_what,
                                                   const float* __restrict__ w1,
                                                   const float* __restrict__ b1,
                                                   float* __restrict__ hid,
                                                   const int* __restrict__ comp,
                                                   const int* __restrict__ cnt) {
    const int ci = blockIdx.x;
    if (ci >= safe_count(cnt)) return;
    const int orig = min(max(comp[ci], 0), 127);
    const int h = threadIdx.x;
    const float* zr = z_what + orig * D_IN;   // uniform per block -> scalar loads
    float acc = b1[h];
#pragma unroll
    for (int d = 0; d < D_IN; ++d)
        acc = fmaf(zr[d], w1[d * H1 + h], acc);
    hid[ci * H1 + h] = fmaxf(acc, 0.0f);
}

// ---------------- Kernel 3: dec[ci] = sigmoid(hid[ci] @ w2 + b2) -------------
// Block = 1024 threads = 4 k-groups x 256 cols. Each group: 16 rows x 256 cols
// over a 128-wide K chunk (8-deep double-buffered w2 prefetch). Groups 1..3
// write partials to LDS; group 0 reduces + sigmoid + stores.
// NOTE: epilogue MUST be statically unrolled — a runtime-bounded loop over
// acc[r] demotes acc[] to scratch (HBM traffic explosion, seen in R3).
__global__ __launch_bounds__(1024) void mlp2_kernel(const float* __restrict__ hid,
                                                    const float* __restrict__ w2,
                                                    const float* __restrict__ b2,
                                                    float* __restrict__ dec,
                                                    const int* __restrict__ cnt) {
    const int count = safe_count(cnt);
    const int ci0 = blockIdx.y * 16;
    if (ci0 >= count) return;

    const int kg = threadIdx.x >> 8;          // k-group 0..3
    const int lj = threadIdx.x & 255;         // local col 0..255
    const int j = blockIdx.x * 256 + lj;      // output column 0..12287
    const int kbase = kg * 128;

    __shared__ float sred[3][16][256];        // 48 KB partial-sum staging

    float acc[16];
#pragma unroll
    for (int r = 0; r < 16; ++r) acc[r] = 0.0f;

    const float* hrow = hid + ci0 * H1 + kbase;  // uniform -> scalar-load path
    const float* wp = w2 + (size_t)kbase * OUT2 + j;

    float wa[8], wb[8];
#pragma unroll
    for (int u = 0; u < 8; ++u) wa[u] = wp[(size_t)u * OUT2];

    for (int k0 = 0; k0 < 128; k0 += 16) {
#pragma unroll
        for (int u = 0; u < 8; ++u) wb[u] = wp[(size_t)(k0 + 8 + u) * OUT2];
#pragma unroll
        for (int u = 0; u < 8; ++u)
#pragma unroll
            for (int r = 0; r < 16; ++r)
                acc[r] = fmaf(hrow[r * H1 + k0 + u], wa[u], acc[r]);
        if (k0 + 16 < 128) {
#pragma unroll
            for (int u = 0; u < 8; ++u) wa[u] = wp[(size_t)(k0 + 16 + u) * OUT2];
        }
#pragma unroll
        for (int u = 0; u < 8; ++u)
#pragma unroll
            for (int r = 0; r < 16; ++r)
                acc[r] = fmaf(hrow[r * H1 + k0 + 8 + u], wb[u], acc[r]);
    }

    if (kg > 0) {
#pragma unroll
        for (int r = 0; r < 16; ++r) sred[kg - 1][r][lj] = acc[r];
    }
    __syncthreads();

    if (kg == 0) {
        const float bb = b2[j];
        const int rmax = min(16, count - ci0);
#pragma unroll
        for (int r = 0; r < 16; ++r) {          // static unroll + predicate:
            if (r < rmax) {                     // keeps acc[] in VGPRs
                float x = acc[r] + sred[0][r][lj] + sred[1][r][lj] + sred[2][r][lj] + bb;
                float v = 1.0f / (1.0f + __expf(-x));
                dec[(size_t)(ci0 + r) * OUT2 + j] = v;
            }
        }
    }
}

// ---------------- Kernel 4: composite --------------------------------------
__global__ __launch_bounds__(256) void composite_kernel(const float* __restrict__ dec,
                                                        const float* __restrict__ obj,
                                                        float* __restrict__ out) {
    const int pix = blockIdx.x * 256 + threadIdx.x;  // 0..173055
    const int b = blockIdx.y;
    const int h = pix / IMAGE_SIZE;
    const int w = pix - h * IMAGE_SIZE;

    __shared__ float sobj[32 * 8];
    for (int k = threadIdx.x; k < 32 * 8; k += 256) sobj[k] = obj[b * 32 * 8 + k];
    __syncthreads();

    const float u = fmaf((float)w, 2.0f / 415.0f, -1.0f);
    const float v = fmaf((float)h, 2.0f / 415.0f, -1.0f);

    float a0 = 0.0f, a1 = 0.0f, a2 = 0.0f;

    for (int n = 0; n < 32; ++n) {
        const float wgt = sobj[n * 8 + 4];
        if (wgt == 0.0f) continue;
        const float gx = (u - sobj[n * 8 + 0]) * sobj[n * 8 + 2];
        const float gy = (v - sobj[n * 8 + 1]) * sobj[n * 8 + 3];
        const float px = (gx + 1.0f) * (0.5f * (DECODED - 1));  // *31.5
        const float py = (gy + 1.0f) * (0.5f * (DECODED - 1));
        if (px <= -1.0f || px >= (float)DECODED || py <= -1.0f || py >= (float)DECODED)
            continue;  // all four corners invalid -> contributes 0

        const float x0f = floorf(px), y0f = floorf(py);
        const int x0 = (int)x0f, y0 = (int)y0f;
        const float wx1 = px - x0f, wx0 = 1.0f - wx1;
        const float wy1 = py - y0f, wy0 = 1.0f - wy1;

        const bool vx0 = (x0 >= 0) & (x0 <= DECODED - 1);
        const bool vx1 = (x0 + 1 >= 0) & (x0 + 1 <= DECODED - 1);
        const bool vy0 = (y0 >= 0) & (y0 <= DECODED - 1);
        const bool vy1 = (y0 + 1 >= 0) & (y0 + 1 <= DECODED - 1);

        const int xc0 = min(max(x0, 0), DECODED - 1);
        const int xc1 = min(max(x0 + 1, 0), DECODED - 1);
        const int yc0 = min(max(y0, 0), DECODED - 1);
        const int yc1 = min(max(y0 + 1, 0), DECODED - 1);

        const float w00 = wx0 * wy0 * (float)(vx0 && vy0);
        const float w10 = wx1 * wy0 * (float)(vx1 && vy0);
        const float w01 = wx0 * wy1 * (float)(vx0 && vy1);
        const float w11 = wx1 * wy1 * (float)(vx1 && vy1);

        const int slot = min(max((int)sobj[n * 8 + 5], 0), 127);  // clamp: no wild addr
        const float* base = dec + (size_t)slot * OUT2;
        const int i00 = yc0 * DECODED + xc0;
        const int i10 = yc0 * DECODED + xc1;
        const int i01 = yc1 * DECODED + xc0;
        const int i11 = yc1 * DECODED + xc1;

        {
            const float* p = base;  // channel 0
            float g = w00 * p[i00] + w10 * p[i10] + w01 * p[i01] + w11 * p[i11];
            a0 = fmaf(wgt, g, a0);
        }
        {
            const float* p = base + 4096;  // channel 1
            float g = w00 * p[i00] + w10 * p[i10] + w01 * p[i01] + w11 * p[i11];
            a1 = fmaf(wgt, g, a1);
        }
        {
            const float* p = base + 8192;  // channel 2
            float g = w00 * p[i00] + w10 * p[i10] + w01 * p[i01] + w11 * p[i11];
            a2 = fmaf(wgt, g, a2);
        }
    }

    out[((size_t)(b * 3 + 0) * IMAGE_SIZE + h) * IMAGE_SIZE + w] = a0;
    out[((size_t)(b * 3 + 1) * IMAGE_SIZE + h) * IMAGE_SIZE + w] = a1;
    out[((size_t)(b * 3 + 2) * IMAGE_SIZE + h) * IMAGE_SIZE + w] = a2;
}

extern "C" void kernel_launch(void* const* d_in, const int* in_sizes, int n_in,
                              void* d_out, int out_size, void* d_ws, size_t ws_size,
                              hipStream_t stream) {
    const float* z_where   = (const float*)d_in[0];   // [4,32,4]
    const int*   z_present = (const int*)d_in[1];     // [4,32,1]
    const float* z_what    = (const float*)d_in[2];   // [4,32,64]
    const float* z_depth   = (const float*)d_in[3];   // [4,32,1]
    const float* w1 = (const float*)d_in[4];          // [64,512]
    const float* b1 = (const float*)d_in[5];          // [512]
    const float* w2 = (const float*)d_in[6];          // [512,12288]
    const float* b2 = (const float*)d_in[7];          // [12288]
    float* out = (float*)d_out;                       // [4,3,416,416] f32

    char* ws = (char*)d_ws;
    float* dec = (float*)ws;                              // 6,291,456 B (by compact slot)
    float* hid = (float*)(ws + 6291456);                  //   262,144 B (by compact slot)
    float* obj = (float*)(ws + 6291456 + 262144);         //     4,096 B
    int*  comp = (int*)(ws + 6291456 + 262144 + 4096);    //       512 B
    int*  cnt  = (int*)(ws + 6291456 + 262144 + 4096 + 512);

    wts_kernel<<<1, 128, 0, stream>>>(z_where, z_present, z_depth, obj, comp, cnt);
    mlp1_kernel<<<M_OBJ, 512, 0, stream>>>(z_what, w1, b1, hid, comp, cnt);
    mlp2_kernel<<<dim3(48, 8), 1024, 0, stream>>>(hid, w2, b2, dec, cnt);
    composite_kernel<<<dim3(NPIX / 256, 4), 256, 0, stream>>>(dec, obj, out);
}

// Round 6
// 73.487 us; speedup vs baseline: 3.2148x; 3.0612x over previous
//
#include <hip/hip_runtime.h>
#include <hip/hip_bf16.h>

#define IMAGE_SIZE 416
#define DECODED 64
#define NPIX (IMAGE_SIZE * IMAGE_SIZE)   // 173056
#define M_OBJ 128                        // B*N = 4*32
#define D_IN 64
#define H1 512
#define OUT2 12288                       // 3*64*64
#define KCHUNKS 4
#define KSUB 128                         // 512 / 4

// ---------------- Kernel 1: per-object params + present-compaction ----------
// obj layout per object (8 floats): tx, ty, inv_sx, inv_sy, weight, slot, 0,0
__global__ __launch_bounds__(128) void wts_kernel(const float* __restrict__ z_where,
                                                  const int* __restrict__ z_present,
                                                  const float* __restrict__ z_depth,
                                                  float* __restrict__ obj,
                                                  int* __restrict__ comp,
                                                  int* __restrict__ cnt) {
    const int t = threadIdx.x;       // 0..127 -> (b = t>>5, n = t&31)
    const int b = t >> 5;
    __shared__ float sd[128];
    __shared__ float se[128];
    __shared__ int spres[128];
    __shared__ int sslot[128];

    const int pres = z_present[t];
    spres[t] = pres;
    const float d = pres ? z_depth[t] : -1000.0f;
    sd[t] = d;
    __syncthreads();

    float m = -1e30f;
#pragma unroll
    for (int k = 0; k < 32; ++k) m = fmaxf(m, sd[(b << 5) + k]);
    const float e = expf(d - m);
    se[t] = e;
    __syncthreads();

    float s = 0.0f;
#pragma unroll
    for (int k = 0; k < 32; ++k) s += se[(b << 5) + k];
    const float wgt = pres ? (e / s) : 0.0f;

    if (t == 0) {
        for (int i = 0; i < 128; ++i) comp[i] = i;  // init: any stray read is safe
        int c = 0;
        for (int i = 0; i < 128; ++i) {
            sslot[i] = spres[i] ? c : -1;
            if (spres[i]) comp[c++] = i;
        }
        *cnt = c;
    }
    __syncthreads();

    const float xc = z_where[t * 4 + 0];
    const float yc = z_where[t * 4 + 1];
    const float ww = z_where[t * 4 + 2];
    const float hh = z_where[t * 4 + 3];
    float* o = obj + t * 8;
    o[0] = 2.0f * xc - 1.0f;
    o[1] = 2.0f * yc - 1.0f;
    o[2] = 1.0f / fmaxf(ww, 0.001f);
    o[3] = 1.0f / fmaxf(hh, 0.001f);
    o[4] = wgt;
    o[5] = (float)sslot[t];
    o[6] = 0.0f; o[7] = 0.0f;
}

__device__ __forceinline__ int safe_count(const int* cnt) {
    int c = *cnt;
    return min(max(c, 1), 128);   // never trust workspace state for addressing
}

// ---------------- Kernel 2: hid[ci] = relu(z_what[comp[ci]] @ w1 + b1) -------
__global__ __launch_bounds__(512) void mlp1_kernel(const float* __restrict__ z_what,
                                                   const float* __restrict__ w1,
                                                   const float* __restrict__ b1,
                                                   float* __restrict__ hid,
                                                   const int* __restrict__ comp,
                                                   const int* __restrict__ cnt) {
    const int ci = blockIdx.x;
    if (ci >= safe_count(cnt)) return;
    const int orig = min(max(comp[ci], 0), 127);
    const int h = threadIdx.x;
    const float* zr = z_what + orig * D_IN;   // uniform per block -> scalar loads
    float acc = b1[h];
#pragma unroll
    for (int d = 0; d < D_IN; ++d)
        acc = fmaf(zr[d], w1[d * H1 + h], acc);
    hid[ci * H1 + h] = fmaxf(acc, 0.0f);
}

// ---------------- Kernel 3a: split-K partial GEMM ---------------------------
// grid (48 col-tiles, 8 row-tiles, 4 k-chunks); block 256 (proven spill-free
// shape: VGPR ~40). Each block: 16 rows x 256 cols over K-chunk of 128.
// 1536 blocks x 4 waves = ~6 waves/SIMD -> latency hidden by TLP.
__global__ __launch_bounds__(256) void mlp2_partial(const float* __restrict__ hid,
                                                    const float* __restrict__ w2,
                                                    float* __restrict__ partials,
                                                    const int* __restrict__ cnt) {
    const int count = safe_count(cnt);
    const int ci0 = blockIdx.y * 16;
    if (ci0 >= count) return;

    const int j = blockIdx.x * 256 + threadIdx.x;
    const int kc = blockIdx.z;
    const int kbase = kc * KSUB;

    float acc[16];
#pragma unroll
    for (int r = 0; r < 16; ++r) acc[r] = 0.0f;

    const float* hrow = hid + ci0 * H1 + kbase;       // uniform -> scalar path
    const float* wp = w2 + (size_t)kbase * OUT2 + j;

    float wa[8], wb[8];
#pragma unroll
    for (int u = 0; u < 8; ++u) wa[u] = wp[(size_t)u * OUT2];

    for (int k0 = 0; k0 < KSUB; k0 += 16) {
#pragma unroll
        for (int u = 0; u < 8; ++u) wb[u] = wp[(size_t)(k0 + 8 + u) * OUT2];
#pragma unroll
        for (int u = 0; u < 8; ++u)
#pragma unroll
            for (int r = 0; r < 16; ++r)
                acc[r] = fmaf(hrow[r * H1 + k0 + u], wa[u], acc[r]);
        if (k0 + 16 < KSUB) {
#pragma unroll
            for (int u = 0; u < 8; ++u) wa[u] = wp[(size_t)(k0 + 16 + u) * OUT2];
        }
#pragma unroll
        for (int u = 0; u < 8; ++u)
#pragma unroll
            for (int r = 0; r < 16; ++r)
                acc[r] = fmaf(hrow[r * H1 + k0 + 8 + u], wb[u], acc[r]);
    }

    const int rmax = min(16, count - ci0);
    float* pout = partials + (size_t)kc * 128 * OUT2;
#pragma unroll
    for (int r = 0; r < 16; ++r) {          // static unroll + predicate
        if (r < rmax)
            pout[(size_t)(ci0 + r) * OUT2 + j] = acc[r];
    }
}

// ---------------- Kernel 3b: reduce partials + bias + sigmoid ---------------
__global__ __launch_bounds__(256) void mlp2_reduce(const float* __restrict__ partials,
                                                   const float* __restrict__ b2,
                                                   float* __restrict__ dec,
                                                   const int* __restrict__ cnt) {
    const int count = safe_count(cnt);
    const int ci0 = blockIdx.y * 16;
    if (ci0 >= count) return;
    const int j = blockIdx.x * 256 + threadIdx.x;
    const float bb = b2[j];
    const int rmax = min(16, count - ci0);
    const size_t koff = (size_t)128 * OUT2;
#pragma unroll
    for (int r = 0; r < 16; ++r) {
        if (r < rmax) {
            const size_t base = (size_t)(ci0 + r) * OUT2 + j;
            float x = bb + partials[base] + partials[base + koff]
                         + partials[base + 2 * koff] + partials[base + 3 * koff];
            dec[base] = 1.0f / (1.0f + __expf(-x));
        }
    }
}

// ---------------- Kernel 3-mono: fallback if ws too small --------------------
__global__ __launch_bounds__(256) void mlp2_mono(const float* __restrict__ hid,
                                                 const float* __restrict__ w2,
                                                 const float* __restrict__ b2,
                                                 float* __restrict__ dec,
                                                 const int* __restrict__ cnt) {
    const int count = safe_count(cnt);
    const int ci0 = blockIdx.y * 16;
    if (ci0 >= count) return;
    const int j = blockIdx.x * 256 + threadIdx.x;
    float acc[16];
#pragma unroll
    for (int r = 0; r < 16; ++r) acc[r] = 0.0f;
    const float* hrow = hid + ci0 * H1;
    const float* wp = w2 + j;
    float wa[8], wb[8];
#pragma unroll
    for (int u = 0; u < 8; ++u) wa[u] = wp[(size_t)u * OUT2];
    for (int k0 = 0; k0 < 512; k0 += 16) {
#pragma unroll
        for (int u = 0; u < 8; ++u) wb[u] = wp[(size_t)(k0 + 8 + u) * OUT2];
#pragma unroll
        for (int u = 0; u < 8; ++u)
#pragma unroll
            for (int r = 0; r < 16; ++r)
                acc[r] = fmaf(hrow[r * H1 + k0 + u], wa[u], acc[r]);
        if (k0 + 16 < 512) {
#pragma unroll
            for (int u = 0; u < 8; ++u) wa[u] = wp[(size_t)(k0 + 16 + u) * OUT2];
        }
#pragma unroll
        for (int u = 0; u < 8; ++u)
#pragma unroll
            for (int r = 0; r < 16; ++r)
                acc[r] = fmaf(hrow[r * H1 + k0 + 8 + u], wb[u], acc[r]);
    }
    const float bb = b2[j];
    const int rmax = min(16, count - ci0);
#pragma unroll
    for (int r = 0; r < 16; ++r) {
        if (r < rmax) {
            float x = acc[r] + bb;
            dec[(size_t)(ci0 + r) * OUT2 + j] = 1.0f / (1.0f + __expf(-x));
        }
    }
}

// ---------------- Kernel 4: composite --------------------------------------
__global__ __launch_bounds__(256) void composite_kernel(const float* __restrict__ dec,
                                                        const float* __restrict__ obj,
                                                        float* __restrict__ out) {
    const int pix = blockIdx.x * 256 + threadIdx.x;  // 0..173055
    const int b = blockIdx.y;
    const int h = pix / IMAGE_SIZE;
    const int w = pix - h * IMAGE_SIZE;

    __shared__ float sobj[32 * 8];
    for (int k = threadIdx.x; k < 32 * 8; k += 256) sobj[k] = obj[b * 32 * 8 + k];
    __syncthreads();

    const float u = fmaf((float)w, 2.0f / 415.0f, -1.0f);
    const float v = fmaf((float)h, 2.0f / 415.0f, -1.0f);

    float a0 = 0.0f, a1 = 0.0f, a2 = 0.0f;

    for (int n = 0; n < 32; ++n) {
        const float wgt = sobj[n * 8 + 4];
        if (wgt == 0.0f) continue;
        const float gx = (u - sobj[n * 8 + 0]) * sobj[n * 8 + 2];
        const float gy = (v - sobj[n * 8 + 1]) * sobj[n * 8 + 3];
        const float px = (gx + 1.0f) * (0.5f * (DECODED - 1));  // *31.5
        const float py = (gy + 1.0f) * (0.5f * (DECODED - 1));
        if (px <= -1.0f || px >= (float)DECODED || py <= -1.0f || py >= (float)DECODED)
            continue;  // all four corners invalid -> contributes 0

        const float x0f = floorf(px), y0f = floorf(py);
        const int x0 = (int)x0f, y0 = (int)y0f;
        const float wx1 = px - x0f, wx0 = 1.0f - wx1;
        const float wy1 = py - y0f, wy0 = 1.0f - wy1;

        const bool vx0 = (x0 >= 0) & (x0 <= DECODED - 1);
        const bool vx1 = (x0 + 1 >= 0) & (x0 + 1 <= DECODED - 1);
        const bool vy0 = (y0 >= 0) & (y0 <= DECODED - 1);
        const bool vy1 = (y0 + 1 >= 0) & (y0 + 1 <= DECODED - 1);

        const int xc0 = min(max(x0, 0), DECODED - 1);
        const int xc1 = min(max(x0 + 1, 0), DECODED - 1);
        const int yc0 = min(max(y0, 0), DECODED - 1);
        const int yc1 = min(max(y0 + 1, 0), DECODED - 1);

        const float w00 = wx0 * wy0 * (float)(vx0 && vy0);
        const float w10 = wx1 * wy0 * (float)(vx1 && vy0);
        const float w01 = wx0 * wy1 * (float)(vx0 && vy1);
        const float w11 = wx1 * wy1 * (float)(vx1 && vy1);

        const int slot = min(max((int)sobj[n * 8 + 5], 0), 127);  // clamp: no wild addr
        const float* base = dec + (size_t)slot * OUT2;
        const int i00 = yc0 * DECODED + xc0;
        const int i10 = yc0 * DECODED + xc1;
        const int i01 = yc1 * DECODED + xc0;
        const int i11 = yc1 * DECODED + xc1;

        {
            const float* p = base;  // channel 0
            float g = w00 * p[i00] + w10 * p[i10] + w01 * p[i01] + w11 * p[i11];
            a0 = fmaf(wgt, g, a0);
        }
        {
            const float* p = base + 4096;  // channel 1
            float g = w00 * p[i00] + w10 * p[i10] + w01 * p[i01] + w11 * p[i11];
            a1 = fmaf(wgt, g, a1);
        }
        {
            const float* p = base + 8192;  // channel 2
            float g = w00 * p[i00] + w10 * p[i10] + w01 * p[i01] + w11 * p[i11];
            a2 = fmaf(wgt, g, a2);
        }
    }

    out[((size_t)(b * 3 + 0) * IMAGE_SIZE + h) * IMAGE_SIZE + w] = a0;
    out[((size_t)(b * 3 + 1) * IMAGE_SIZE + h) * IMAGE_SIZE + w] = a1;
    out[((size_t)(b * 3 + 2) * IMAGE_SIZE + h) * IMAGE_SIZE + w] = a2;
}

extern "C" void kernel_launch(void* const* d_in, const int* in_sizes, int n_in,
                              void* d_out, int out_size, void* d_ws, size_t ws_size,
                              hipStream_t stream) {
    const float* z_where   = (const float*)d_in[0];   // [4,32,4]
    const int*   z_present = (const int*)d_in[1];     // [4,32,1]
    const float* z_what    = (const float*)d_in[2];   // [4,32,64]
    const float* z_depth   = (const float*)d_in[3];   // [4,32,1]
    const float* w1 = (const float*)d_in[4];          // [64,512]
    const float* b1 = (const float*)d_in[5];          // [512]
    const float* w2 = (const float*)d_in[6];          // [512,12288]
    const float* b2 = (const float*)d_in[7];          // [12288]
    float* out = (float*)d_out;                       // [4,3,416,416] f32

    char* ws = (char*)d_ws;
    float* dec      = (float*)ws;                          // 6,291,456 B
    float* hid      = (float*)(ws + 6291456);              //   262,144 B
    float* obj      = (float*)(ws + 6553600);              //     4,096 B
    int*  comp      = (int*)(ws + 6557696);                //       512 B
    int*  cnt       = (int*)(ws + 6558208);                //       256 B (pad)
    float* partials = (float*)(ws + 6558464);              // 25,165,824 B
    const size_t ws_needed = 6558464 + (size_t)KCHUNKS * 128 * OUT2 * 4;

    wts_kernel<<<1, 128, 0, stream>>>(z_where, z_present, z_depth, obj, comp, cnt);
    mlp1_kernel<<<M_OBJ, 512, 0, stream>>>(z_what, w1, b1, hid, comp, cnt);
    if (ws_size >= ws_needed) {
        mlp2_partial<<<dim3(48, 8, KCHUNKS), 256, 0, stream>>>(hid, w2, partials, cnt);
        mlp2_reduce<<<dim3(48, 8), 256, 0, stream>>>(partials, b2, dec, cnt);
    } else {
        mlp2_mono<<<dim3(48, 8), 256, 0, stream>>>(hid, w2, b2, dec, cnt);
    }
    composite_kernel<<<dim3(NPIX / 256, 4), 256, 0, stream>>>(dec, obj, out);
}

// Round 7
// 52.141 us; speedup vs baseline: 4.5309x; 1.4094x over previous
//
#include <hip/hip_runtime.h>
#include <hip/hip_bf16.h>

#define IMAGE_SIZE 416
#define DECODED 64
#define NPIX (IMAGE_SIZE * IMAGE_SIZE)   // 173056
#define M_OBJ 128                        // B*N = 4*32
#define D_IN 64
#define H1 512
#define OUT2 12288                       // 3*64*64

__device__ __forceinline__ int safe_count(const int* cnt) {
    int c = *cnt;
    return min(max(c, 1), 128);   // never trust workspace state for addressing
}

// ---------------- Kernel 1: front = mlp1 (blocks 0..127) + wts (block 128) --
// obj layout per object (8 floats): tx, ty, inv_sx, inv_sy, weight, slot, 0,0
__global__ __launch_bounds__(512) void front_kernel(const float* __restrict__ z_what,
                                                    const float* __restrict__ w1,
                                                    const float* __restrict__ b1,
                                                    const float* __restrict__ z_where,
                                                    const int* __restrict__ z_present,
                                                    const float* __restrict__ z_depth,
                                                    float* __restrict__ hid,
                                                    float* __restrict__ obj,
                                                    int* __restrict__ cnt) {
    const int bx = blockIdx.x;
    const int t = threadIdx.x;

    if (bx == 128) {
        // ---- wts path: softmax weights + STN constants + count ----
        __shared__ float sd[128];
        __shared__ float se[128];
        __shared__ int spres[128];
        __shared__ int sslot[128];
        int pres = 0;
        float d = 0.0f;
        if (t < 128) {
            pres = z_present[t];
            spres[t] = pres;
            d = pres ? z_depth[t] : -1000.0f;
            sd[t] = d;
        }
        __syncthreads();
        float e = 0.0f;
        if (t < 128) {
            const int b = t >> 5;
            float m = -1e30f;
#pragma unroll
            for (int k = 0; k < 32; ++k) m = fmaxf(m, sd[(b << 5) + k]);
            e = expf(d - m);
            se[t] = e;
        }
        __syncthreads();
        if (t == 0) {
            int c = 0;
            for (int i = 0; i < 128; ++i) {
                sslot[i] = spres[i] ? c : -1;
                if (spres[i]) c++;
            }
            *cnt = c;
        }
        __syncthreads();
        if (t < 128) {
            const int b = t >> 5;
            float s = 0.0f;
#pragma unroll
            for (int k = 0; k < 32; ++k) s += se[(b << 5) + k];
            const float wgt = pres ? (e / s) : 0.0f;
            const float xc = z_where[t * 4 + 0];
            const float yc = z_where[t * 4 + 1];
            const float ww = z_where[t * 4 + 2];
            const float hh = z_where[t * 4 + 3];
            float* o = obj + t * 8;
            o[0] = 2.0f * xc - 1.0f;
            o[1] = 2.0f * yc - 1.0f;
            o[2] = 1.0f / fmaxf(ww, 0.001f);
            o[3] = 1.0f / fmaxf(hh, 0.001f);
            o[4] = wgt;
            o[5] = (float)sslot[t];
            o[6] = 0.0f; o[7] = 0.0f;
        }
        return;
    }

    // ---- mlp1 path: compact slot bx -> find orig row by scanning presence ----
    __shared__ int pres_s[128];
    __shared__ int sorig;
    if (t < 128) pres_s[t] = z_present[t];
    __syncthreads();
    if (t == 0) {
        int c = 0, orig = -1;
        for (int i = 0; i < 128; ++i) {
            if (pres_s[i]) {
                if (c == bx) { orig = i; break; }
                ++c;
            }
        }
        sorig = orig;
    }
    __syncthreads();
    const int orig = sorig;
    if (orig < 0) return;               // fewer than bx+1 present objects

    const int h = t;                    // 0..511
    const float* zr = z_what + orig * D_IN;   // uniform per block -> scalar loads
    float acc = b1[h];
#pragma unroll
    for (int d = 0; d < D_IN; ++d)
        acc = fmaf(zr[d], w1[d * H1 + h], acc);
    hid[bx * H1 + h] = fmaxf(acc, 0.0f);
}

// ---------------- Kernel 2: dec[ci] = sigmoid(hid[ci] @ w2 + b2) -------------
// In-block split-K: 512 threads = 8 k-groups x 64 cols; each k-group covers
// K=64 with 8-deep double-buffered w2 prefetch; LDS staging (32 KB) then an
// all-thread reduce + bias + sigmoid. No partials in HBM, no reduce kernel.
// Grid (192 col-tiles, 8 row-tiles); active blocks x 8 waves ~= 6 waves/SIMD.
__global__ __launch_bounds__(512) void mlp2_fused(const float* __restrict__ hid,
                                                  const float* __restrict__ w2,
                                                  const float* __restrict__ b2,
                                                  float* __restrict__ dec,
                                                  const int* __restrict__ cnt) {
    const int count = safe_count(cnt);
    const int ci0 = blockIdx.y * 16;
    if (ci0 >= count) return;

    const int kg = threadIdx.x >> 6;          // k-group 0..7 (== wave id)
    const int c  = threadIdx.x & 63;          // local col 0..63
    const int j  = blockIdx.x * 64 + c;       // output column 0..12287
    // wave-uniform by construction; force scalar path for hid loads
    const int kbase = __builtin_amdgcn_readfirstlane(kg * 64);

    __shared__ float sred[8][16][64];         // 32 KB

    float acc[16];
#pragma unroll
    for (int r = 0; r < 16; ++r) acc[r] = 0.0f;

    const float* hrow = hid + ci0 * H1 + kbase;      // uniform -> s_load path
    const float* wp = w2 + (size_t)kbase * OUT2 + j;

    float wa[8], wb[8];
#pragma unroll
    for (int u = 0; u < 8; ++u) wa[u] = wp[(size_t)u * OUT2];

    for (int k0 = 0; k0 < 64; k0 += 16) {
#pragma unroll
        for (int u = 0; u < 8; ++u) wb[u] = wp[(size_t)(k0 + 8 + u) * OUT2];
#pragma unroll
        for (int u = 0; u < 8; ++u)
#pragma unroll
            for (int r = 0; r < 16; ++r)
                acc[r] = fmaf(hrow[r * H1 + k0 + u], wa[u], acc[r]);
        if (k0 + 16 < 64) {
#pragma unroll
            for (int u = 0; u < 8; ++u) wa[u] = wp[(size_t)(k0 + 16 + u) * OUT2];
        }
#pragma unroll
        for (int u = 0; u < 8; ++u)
#pragma unroll
            for (int r = 0; r < 16; ++r)
                acc[r] = fmaf(hrow[r * H1 + k0 + 8 + u], wb[u], acc[r]);
    }

#pragma unroll
    for (int r = 0; r < 16; ++r) sred[kg][r][c] = acc[r];
    __syncthreads();

    // all 512 threads reduce: thread handles rows kg and kg+8 at col c
    const int r0 = kg;
    float s0 = 0.0f, s1 = 0.0f;
#pragma unroll
    for (int g = 0; g < 8; ++g) {
        s0 += sred[g][r0][c];
        s1 += sred[g][r0 + 8][c];
    }
    const float bb = b2[j];
    const int rmax = min(16, count - ci0);
    if (r0 < rmax)
        dec[(size_t)(ci0 + r0) * OUT2 + j] = 1.0f / (1.0f + __expf(-(s0 + bb)));
    if (r0 + 8 < rmax)
        dec[(size_t)(ci0 + r0 + 8) * OUT2 + j] = 1.0f / (1.0f + __expf(-(s1 + bb)));
}

// ---------------- Kernel 3: composite --------------------------------------
__global__ __launch_bounds__(256) void composite_kernel(const float* __restrict__ dec,
                                                        const float* __restrict__ obj,
                                                        float* __restrict__ out) {
    const int pix = blockIdx.x * 256 + threadIdx.x;  // 0..173055
    const int b = blockIdx.y;
    const int h = pix / IMAGE_SIZE;
    const int w = pix - h * IMAGE_SIZE;

    __shared__ float sobj[32 * 8];
    for (int k = threadIdx.x; k < 32 * 8; k += 256) sobj[k] = obj[b * 32 * 8 + k];
    __syncthreads();

    const float u = fmaf((float)w, 2.0f / 415.0f, -1.0f);
    const float v = fmaf((float)h, 2.0f / 415.0f, -1.0f);

    float a0 = 0.0f, a1 = 0.0f, a2 = 0.0f;

    for (int n = 0; n < 32; ++n) {
        const float wgt = sobj[n * 8 + 4];
        if (wgt == 0.0f) continue;
        const float gx = (u - sobj[n * 8 + 0]) * sobj[n * 8 + 2];
        const float gy = (v - sobj[n * 8 + 1]) * sobj[n * 8 + 3];
        const float px = (gx + 1.0f) * (0.5f * (DECODED - 1));  // *31.5
        const float py = (gy + 1.0f) * (0.5f * (DECODED - 1));
        if (px <= -1.0f || px >= (float)DECODED || py <= -1.0f || py >= (float)DECODED)
            continue;  // all four corners invalid -> contributes 0

        const float x0f = floorf(px), y0f = floorf(py);
        const int x0 = (int)x0f, y0 = (int)y0f;
        const float wx1 = px - x0f, wx0 = 1.0f - wx1;
        const float wy1 = py - y0f, wy0 = 1.0f - wy1;

        const bool vx0 = (x0 >= 0) & (x0 <= DECODED - 1);
        const bool vx1 = (x0 + 1 >= 0) & (x0 + 1 <= DECODED - 1);
        const bool vy0 = (y0 >= 0) & (y0 <= DECODED - 1);
        const bool vy1 = (y0 + 1 >= 0) & (y0 + 1 <= DECODED - 1);

        const int xc0 = min(max(x0, 0), DECODED - 1);
        const int xc1 = min(max(x0 + 1, 0), DECODED - 1);
        const int yc0 = min(max(y0, 0), DECODED - 1);
        const int yc1 = min(max(y0 + 1, 0), DECODED - 1);

        const float w00 = wx0 * wy0 * (float)(vx0 && vy0);
        const float w10 = wx1 * wy0 * (float)(vx1 && vy0);
        const float w01 = wx0 * wy1 * (float)(vx0 && vy1);
        const float w11 = wx1 * wy1 * (float)(vx1 && vy1);

        const int slot = min(max((int)sobj[n * 8 + 5], 0), 127);  // clamp: no wild addr
        const float* base = dec + (size_t)slot * OUT2;
        const int i00 = yc0 * DECODED + xc0;
        const int i10 = yc0 * DECODED + xc1;
        const int i01 = yc1 * DECODED + xc0;
        const int i11 = yc1 * DECODED + xc1;

        {
            const float* p = base;  // channel 0
            float g = w00 * p[i00] + w10 * p[i10] + w01 * p[i01] + w11 * p[i11];
            a0 = fmaf(wgt, g, a0);
        }
        {
            const float* p = base + 4096;  // channel 1
            float g = w00 * p[i00] + w10 * p[i10] + w01 * p[i01] + w11 * p[i11];
            a1 = fmaf(wgt, g, a1);
        }
        {
            const float* p = base + 8192;  // channel 2
            float g = w00 * p[i00] + w10 * p[i10] + w01 * p[i01] + w11 * p[i11];
            a2 = fmaf(wgt, g, a2);
        }
    }

    out[((size_t)(b * 3 + 0) * IMAGE_SIZE + h) * IMAGE_SIZE + w] = a0;
    out[((size_t)(b * 3 + 1) * IMAGE_SIZE + h) * IMAGE_SIZE + w] = a1;
    out[((size_t)(b * 3 + 2) * IMAGE_SIZE + h) * IMAGE_SIZE + w] = a2;
}

extern "C" void kernel_launch(void* const* d_in, const int* in_sizes, int n_in,
                              void* d_out, int out_size, void* d_ws, size_t ws_size,
                              hipStream_t stream) {
    const float* z_where   = (const float*)d_in[0];   // [4,32,4]
    const int*   z_present = (const int*)d_in[1];     // [4,32,1]
    const float* z_what    = (const float*)d_in[2];   // [4,32,64]
    const float* z_depth   = (const float*)d_in[3];   // [4,32,1]
    const float* w1 = (const float*)d_in[4];          // [64,512]
    const float* b1 = (const float*)d_in[5];          // [512]
    const float* w2 = (const float*)d_in[6];          // [512,12288]
    const float* b2 = (const float*)d_in[7];          // [12288]
    float* out = (float*)d_out;                       // [4,3,416,416] f32

    char* ws = (char*)d_ws;
    float* dec = (float*)ws;                          // 6,291,456 B (by compact slot)
    float* hid = (float*)(ws + 6291456);              //   262,144 B (by compact slot)
    float* obj = (float*)(ws + 6553600);              //     4,096 B
    int*  cnt  = (int*)(ws + 6557696);                //       256 B

    front_kernel<<<129, 512, 0, stream>>>(z_what, w1, b1, z_where, z_present,
                                          z_depth, hid, obj, cnt);
    mlp2_fused<<<dim3(192, 8), 512, 0, stream>>>(hid, w2, b2, dec, cnt);
    composite_kernel<<<dim3(NPIX / 256, 4), 256, 0, stream>>>(dec, obj, out);
}

// Round 8
// 49.075 us; speedup vs baseline: 4.8139x; 1.0625x over previous
//
#include <hip/hip_runtime.h>
#include <hip/hip_bf16.h>

#define IMAGE_SIZE 416
#define DECODED 64
#define NPIX (IMAGE_SIZE * IMAGE_SIZE)   // 173056
#define M_OBJ 128                        // B*N = 4*32
#define D_IN 64
#define H1 512
#define OUT2 12288                       // 3*64*64

__device__ __forceinline__ int safe_count(const int* cnt) {
    int c = *cnt;
    return min(max(c, 1), 128);   // never trust workspace state for addressing
}

// ---------------- Kernel 1: front = mlp1 (blocks 0..127) + wts (block 128) --
// obj layout per object (8 floats): tx, ty, inv_sx, inv_sy, weight, slot, 0,0
__global__ __launch_bounds__(512) void front_kernel(const float* __restrict__ z_what,
                                                    const float* __restrict__ w1,
                                                    const float* __restrict__ b1,
                                                    const float* __restrict__ z_where,
                                                    const int* __restrict__ z_present,
                                                    const float* __restrict__ z_depth,
                                                    float* __restrict__ hid,
                                                    float* __restrict__ obj,
                                                    int* __restrict__ cnt) {
    const int bx = blockIdx.x;
    const int t = threadIdx.x;

    if (bx == 128) {
        // ---- wts path: softmax weights + STN constants + count ----
        __shared__ float sd[128];
        __shared__ float se[128];
        __shared__ int spres[128];
        __shared__ int sslot[128];
        int pres = 0;
        float d = 0.0f;
        if (t < 128) {
            pres = z_present[t];
            spres[t] = pres;
            d = pres ? z_depth[t] : -1000.0f;
            sd[t] = d;
        }
        __syncthreads();
        float e = 0.0f;
        if (t < 128) {
            const int b = t >> 5;
            float m = -1e30f;
#pragma unroll
            for (int k = 0; k < 32; ++k) m = fmaxf(m, sd[(b << 5) + k]);
            e = expf(d - m);
            se[t] = e;
        }
        __syncthreads();
        if (t == 0) {
            int c = 0;
            for (int i = 0; i < 128; ++i) {
                sslot[i] = spres[i] ? c : -1;
                if (spres[i]) c++;
            }
            *cnt = c;
        }
        __syncthreads();
        if (t < 128) {
            const int b = t >> 5;
            float s = 0.0f;
#pragma unroll
            for (int k = 0; k < 32; ++k) s += se[(b << 5) + k];
            const float wgt = pres ? (e / s) : 0.0f;
            const float xc = z_where[t * 4 + 0];
            const float yc = z_where[t * 4 + 1];
            const float ww = z_where[t * 4 + 2];
            const float hh = z_where[t * 4 + 3];
            float* o = obj + t * 8;
            o[0] = 2.0f * xc - 1.0f;
            o[1] = 2.0f * yc - 1.0f;
            o[2] = 1.0f / fmaxf(ww, 0.001f);
            o[3] = 1.0f / fmaxf(hh, 0.001f);
            o[4] = wgt;
            o[5] = (float)sslot[t];
            o[6] = 0.0f; o[7] = 0.0f;
        }
        return;
    }

    // ---- mlp1 path: compact slot bx -> find orig row by scanning presence ----
    __shared__ int pres_s[128];
    __shared__ int sorig;
    if (t < 128) pres_s[t] = z_present[t];
    __syncthreads();
    if (t == 0) {
        int c = 0, orig = -1;
        for (int i = 0; i < 128; ++i) {
            if (pres_s[i]) {
                if (c == bx) { orig = i; break; }
                ++c;
            }
        }
        sorig = orig;
    }
    __syncthreads();
    const int orig = sorig;
    if (orig < 0) return;               // fewer than bx+1 present objects

    const int h = t;                    // 0..511
    const float* zr = z_what + orig * D_IN;   // uniform per block -> scalar loads
    float acc = b1[h];
#pragma unroll
    for (int d = 0; d < D_IN; ++d)
        acc = fmaf(zr[d], w1[d * H1 + h], acc);
    hid[bx * H1 + h] = fmaxf(acc, 0.0f);
}

// ---------------- Kernel 2: dec[ci] = sigmoid(hid[ci] @ w2 + b2) -------------
// In-block split-K: 512 threads = 8 k-groups x 64 cols, K'=64 each.
// hid tile (16x512 = 32 KB) staged in LDS -> broadcast ds_read_b128 (kills the
// s_load serialization that capped VALUBusy at ~10%). Same 32 KB is reused
// (after a barrier) as the split-K reduce buffer. XCD-aware block swizzle
// gives each XCD a contiguous 1536-col stripe of w2 (3 MB, L2-resident).
__global__ __launch_bounds__(512) void mlp2_fused(const float* __restrict__ hid,
                                                  const float* __restrict__ w2,
                                                  const float* __restrict__ b2,
                                                  float* __restrict__ dec,
                                                  const int* __restrict__ cnt) {
    const int count = safe_count(cnt);

    // XCD swizzle: lin = a + 8*b + 192*c (a=xcd, b in [0,24), c=row-tile)
    const int lin = blockIdx.x + blockIdx.y * gridDim.x;   // 0..1535
    const int jt  = (lin & 7) * 24 + ((lin >> 3) % 24);    // col-tile 0..191
    const int rt  = lin / 192;                             // row-tile 0..7
    const int ci0 = rt * 16;
    if (ci0 >= count) return;

    const int kg = threadIdx.x >> 6;          // k-group 0..7 (== wave id)
    const int c  = threadIdx.x & 63;          // local col 0..63
    const int j  = jt * 64 + c;               // output column 0..12287
    const int kbase = __builtin_amdgcn_readfirstlane(kg * 64);

    __shared__ float smem[8192];              // 32 KB: hid tile, then sred

    // ---- stage hid[ci0..ci0+16][0..512) into LDS (coalesced float4) ----
    {
        const float4* g4 = (const float4*)(hid + ci0 * H1);
        float4* s4 = (float4*)smem;
#pragma unroll
        for (int i = 0; i < 4; ++i)
            s4[threadIdx.x + i * 512] = g4[threadIdx.x + i * 512];
    }
    __syncthreads();

    float acc[16];
#pragma unroll
    for (int r = 0; r < 16; ++r) acc[r] = 0.0f;

    const float* wp = w2 + (size_t)kbase * OUT2 + j;

    float wa[8], wb[8];
#pragma unroll
    for (int u = 0; u < 8; ++u) wa[u] = wp[(size_t)u * OUT2];

    for (int k0 = 0; k0 < 64; k0 += 16) {
#pragma unroll
        for (int u = 0; u < 8; ++u) wb[u] = wp[(size_t)(k0 + 8 + u) * OUT2];
#pragma unroll
        for (int r = 0; r < 16; ++r) {
            const float4 h0 = *(const float4*)&smem[r * 512 + kbase + k0];
            const float4 h1 = *(const float4*)&smem[r * 512 + kbase + k0 + 4];
            acc[r] = fmaf(h0.x, wa[0], acc[r]);
            acc[r] = fmaf(h0.y, wa[1], acc[r]);
            acc[r] = fmaf(h0.z, wa[2], acc[r]);
            acc[r] = fmaf(h0.w, wa[3], acc[r]);
            acc[r] = fmaf(h1.x, wa[4], acc[r]);
            acc[r] = fmaf(h1.y, wa[5], acc[r]);
            acc[r] = fmaf(h1.z, wa[6], acc[r]);
            acc[r] = fmaf(h1.w, wa[7], acc[r]);
        }
        if (k0 + 16 < 64) {
#pragma unroll
            for (int u = 0; u < 8; ++u) wa[u] = wp[(size_t)(k0 + 16 + u) * OUT2];
        }
#pragma unroll
        for (int r = 0; r < 16; ++r) {
            const float4 h0 = *(const float4*)&smem[r * 512 + kbase + k0 + 8];
            const float4 h1 = *(const float4*)&smem[r * 512 + kbase + k0 + 12];
            acc[r] = fmaf(h0.x, wb[0], acc[r]);
            acc[r] = fmaf(h0.y, wb[1], acc[r]);
            acc[r] = fmaf(h0.z, wb[2], acc[r]);
            acc[r] = fmaf(h0.w, wb[3], acc[r]);
            acc[r] = fmaf(h1.x, wb[4], acc[r]);
            acc[r] = fmaf(h1.y, wb[5], acc[r]);
            acc[r] = fmaf(h1.z, wb[6], acc[r]);
            acc[r] = fmaf(h1.w, wb[7], acc[r]);
        }
    }

    // ---- reuse the same 32 KB as sred[8][16][64] ----
    __syncthreads();                          // everyone done reading hid
    float (*sred)[16][64] = (float (*)[16][64])smem;
#pragma unroll
    for (int r = 0; r < 16; ++r) sred[kg][r][c] = acc[r];
    __syncthreads();

    // all 512 threads reduce: thread handles rows kg and kg+8 at col c
    const int r0 = kg;
    float s0 = 0.0f, s1 = 0.0f;
#pragma unroll
    for (int g = 0; g < 8; ++g) {
        s0 += sred[g][r0][c];
        s1 += sred[g][r0 + 8][c];
    }
    const float bb = b2[j];
    const int rmax = min(16, count - ci0);
    if (r0 < rmax)
        dec[(size_t)(ci0 + r0) * OUT2 + j] = 1.0f / (1.0f + __expf(-(s0 + bb)));
    if (r0 + 8 < rmax)
        dec[(size_t)(ci0 + r0 + 8) * OUT2 + j] = 1.0f / (1.0f + __expf(-(s1 + bb)));
}

// ---------------- Kernel 3: composite --------------------------------------
__global__ __launch_bounds__(256) void composite_kernel(const float* __restrict__ dec,
                                                        const float* __restrict__ obj,
                                                        float* __restrict__ out) {
    const int pix = blockIdx.x * 256 + threadIdx.x;  // 0..173055
    const int b = blockIdx.y;
    const int h = pix / IMAGE_SIZE;
    const int w = pix - h * IMAGE_SIZE;

    __shared__ float sobj[32 * 8];
    for (int k = threadIdx.x; k < 32 * 8; k += 256) sobj[k] = obj[b * 32 * 8 + k];
    __syncthreads();

    const float u = fmaf((float)w, 2.0f / 415.0f, -1.0f);
    const float v = fmaf((float)h, 2.0f / 415.0f, -1.0f);

    float a0 = 0.0f, a1 = 0.0f, a2 = 0.0f;

    for (int n = 0; n < 32; ++n) {
        const float wgt = sobj[n * 8 + 4];
        if (wgt == 0.0f) continue;
        const float gx = (u - sobj[n * 8 + 0]) * sobj[n * 8 + 2];
        const float gy = (v - sobj[n * 8 + 1]) * sobj[n * 8 + 3];
        const float px = (gx + 1.0f) * (0.5f * (DECODED - 1));  // *31.5
        const float py = (gy + 1.0f) * (0.5f * (DECODED - 1));
        if (px <= -1.0f || px >= (float)DECODED || py <= -1.0f || py >= (float)DECODED)
            continue;  // all four corners invalid -> contributes 0

        const float x0f = floorf(px), y0f = floorf(py);
        const int x0 = (int)x0f, y0 = (int)y0f;
        const float wx1 = px - x0f, wx0 = 1.0f - wx1;
        const float wy1 = py - y0f, wy0 = 1.0f - wy1;

        const bool vx0 = (x0 >= 0) & (x0 <= DECODED - 1);
        const bool vx1 = (x0 + 1 >= 0) & (x0 + 1 <= DECODED - 1);
        const bool vy0 = (y0 >= 0) & (y0 <= DECODED - 1);
        const bool vy1 = (y0 + 1 >= 0) & (y0 + 1 <= DECODED - 1);

        const int xc0 = min(max(x0, 0), DECODED - 1);
        const int xc1 = min(max(x0 + 1, 0), DECODED - 1);
        const int yc0 = min(max(y0, 0), DECODED - 1);
        const int yc1 = min(max(y0 + 1, 0), DECODED - 1);

        const float w00 = wx0 * wy0 * (float)(vx0 && vy0);
        const float w10 = wx1 * wy0 * (float)(vx1 && vy0);
        const float w01 = wx0 * wy1 * (float)(vx0 && vy1);
        const float w11 = wx1 * wy1 * (float)(vx1 && vy1);

        const int slot = min(max((int)sobj[n * 8 + 5], 0), 127);  // clamp: no wild addr
        const float* base = dec + (size_t)slot * OUT2;
        const int i00 = yc0 * DECODED + xc0;
        const int i10 = yc0 * DECODED + xc1;
        const int i01 = yc1 * DECODED + xc0;
        const int i11 = yc1 * DECODED + xc1;

        {
            const float* p = base;  // channel 0
            float g = w00 * p[i00] + w10 * p[i10] + w01 * p[i01] + w11 * p[i11];
            a0 = fmaf(wgt, g, a0);
        }
        {
            const float* p = base + 4096;  // channel 1
            float g = w00 * p[i00] + w10 * p[i10] + w01 * p[i01] + w11 * p[i11];
            a1 = fmaf(wgt, g, a1);
        }
        {
            const float* p = base + 8192;  // channel 2
            float g = w00 * p[i00] + w10 * p[i10] + w01 * p[i01] + w11 * p[i11];
            a2 = fmaf(wgt, g, a2);
        }
    }

    out[((size_t)(b * 3 + 0) * IMAGE_SIZE + h) * IMAGE_SIZE + w] = a0;
    out[((size_t)(b * 3 + 1) * IMAGE_SIZE + h) * IMAGE_SIZE + w] = a1;
    out[((size_t)(b * 3 + 2) * IMAGE_SIZE + h) * IMAGE_SIZE + w] = a2;
}

extern "C" void kernel_launch(void* const* d_in, const int* in_sizes, int n_in,
                              void* d_out, int out_size, void* d_ws, size_t ws_size,
                              hipStream_t stream) {
    const float* z_where   = (const float*)d_in[0];   // [4,32,4]
    const int*   z_present = (const int*)d_in[1];     // [4,32,1]
    const float* z_what    = (const float*)d_in[2];   // [4,32,64]
    const float* z_depth   = (const float*)d_in[3];   // [4,32,1]
    const float* w1 = (const float*)d_in[4];          // [64,512]
    const float* b1 = (const float*)d_in[5];          // [512]
    const float* w2 = (const float*)d_in[6];          // [512,12288]
    const float* b2 = (const float*)d_in[7];          // [12288]
    float* out = (float*)d_out;                       // [4,3,416,416] f32

    char* ws = (char*)d_ws;
    float* dec = (float*)ws;                          // 6,291,456 B (by compact slot)
    float* hid = (float*)(ws + 6291456);              //   262,144 B (by compact slot)
    float* obj = (float*)(ws + 6553600);              //     4,096 B
    int*  cnt  = (int*)(ws + 6557696);                //       256 B

    front_kernel<<<129, 512, 0, stream>>>(z_what, w1, b1, z_where, z_present,
                                          z_depth, hid, obj, cnt);
    mlp2_fused<<<dim3(192, 8), 512, 0, stream>>>(hid, w2, b2, dec, cnt);
    composite_kernel<<<dim3(NPIX / 256, 4), 256, 0, stream>>>(dec, obj, out);
}